// Round 3
// baseline (886.049 us; speedup 1.0000x reference)
//
#include <hip/hip_runtime.h>

#define D_FEAT 32
#define BNODES 128            // nodes per bucket
#define NB_MAX 1024           // scan block width (>= n_buckets)

// ---- histogram of row>>7 into n_buckets counters (LDS-staged) ----
__global__ void hist_kernel(const int* __restrict__ row, int* __restrict__ cnt,
                            int E, int nb) {
    extern __shared__ int sh[];
    for (int i = threadIdx.x; i < nb; i += blockDim.x) sh[i] = 0;
    __syncthreads();
    int stride = gridDim.x * blockDim.x;
    for (int e = blockIdx.x * blockDim.x + threadIdx.x; e < E; e += stride)
        atomicAdd(&sh[row[e] >> 7], 1);
    __syncthreads();
    for (int i = threadIdx.x; i < nb; i += blockDim.x)
        if (sh[i]) atomicAdd(&cnt[i], sh[i]);
}

// ---- exclusive scan of n_buckets (<=1024) counters, single block ----
__global__ void scan_kernel(const int* __restrict__ cnt, int* __restrict__ offs, int nb) {
    __shared__ int sh[NB_MAX];
    int t = threadIdx.x;
    int v0 = (t < nb) ? cnt[t] : 0;
    sh[t] = v0;
    __syncthreads();
    for (int off = 1; off < NB_MAX; off <<= 1) {
        int v = (t >= off) ? sh[t - off] : 0;
        __syncthreads();
        sh[t] += v;
        __syncthreads();
    }
    if (t < nb) offs[t] = sh[t] - v0;  // exclusive prefix
}

// ---- bin edges into coarse buckets; pack (local_row<<17 | col) ----
__global__ void bin_kernel(const int* __restrict__ row, const int* __restrict__ col,
                           const int* __restrict__ offs, int* __restrict__ fill,
                           unsigned* __restrict__ packed, int E) {
    int e = blockIdx.x * blockDim.x + threadIdx.x;
    if (e >= E) return;
    int r = row[e];
    int c = col[e];
    int b = r >> 7;
    int slot = atomicAdd(&fill[b], 1);
    packed[offs[b] + slot] = ((unsigned)(r & (BNODES - 1)) << 17) | (unsigned)c;
}

// ---- per-bucket LDS-accumulated mean ----
__global__ void __launch_bounds__(256) phase2_kernel(const float* __restrict__ x,
                                                     const unsigned* __restrict__ packed,
                                                     const int* __restrict__ offs,
                                                     const int* __restrict__ cnt,
                                                     float* __restrict__ out, int N) {
    __shared__ float acc[BNODES * D_FEAT];  // 16 KB
    __shared__ int degl[BNODES];
    int t = threadIdx.x;
    for (int i = t; i < BNODES * D_FEAT; i += 256) acc[i] = 0.f;
    for (int i = t; i < BNODES; i += 256) degl[i] = 0;
    __syncthreads();

    int b = blockIdx.x;
    int s = offs[b];
    int n = cnt[b];
    int end = s + n;
    int d = t & 31;   // feature lane
    int g = t >> 5;   // edge subgroup 0..7

    int e = s + g;
    // 4-way unrolled (stride 8 per group): 4 independent gathers in flight
    for (; e + 24 < end; e += 32) {
        unsigned p0 = packed[e];
        unsigned p1 = packed[e + 8];
        unsigned p2 = packed[e + 16];
        unsigned p3 = packed[e + 24];
        float v0 = x[(p0 & 0x1FFFFu) * D_FEAT + d];
        float v1 = x[(p1 & 0x1FFFFu) * D_FEAT + d];
        float v2 = x[(p2 & 0x1FFFFu) * D_FEAT + d];
        float v3 = x[(p3 & 0x1FFFFu) * D_FEAT + d];
        atomicAdd(&acc[(p0 >> 17) * D_FEAT + d], v0);
        atomicAdd(&acc[(p1 >> 17) * D_FEAT + d], v1);
        atomicAdd(&acc[(p2 >> 17) * D_FEAT + d], v2);
        atomicAdd(&acc[(p3 >> 17) * D_FEAT + d], v3);
        if (d == 0) {
            atomicAdd(&degl[p0 >> 17], 1);
            atomicAdd(&degl[p1 >> 17], 1);
            atomicAdd(&degl[p2 >> 17], 1);
            atomicAdd(&degl[p3 >> 17], 1);
        }
    }
    for (; e < end; e += 8) {
        unsigned p = packed[e];
        float v = x[(p & 0x1FFFFu) * D_FEAT + d];
        atomicAdd(&acc[(p >> 17) * D_FEAT + d], v);
        if (d == 0) atomicAdd(&degl[p >> 17], 1);
    }
    __syncthreads();

    // write out this bucket's slab, divided by degree
    int base_node = b * BNODES;
    int nodes_here = min(BNODES, N - base_node);
    for (int i = t; i < nodes_here * D_FEAT; i += 256) {
        float dg = (float)degl[i >> 5];
        out[(size_t)base_node * D_FEAT + i] = acc[i] / fmaxf(dg, 1.0f);
    }
}

// ---------------- launch ----------------

extern "C" void kernel_launch(void* const* d_in, const int* in_sizes, int n_in,
                              void* d_out, int out_size, void* d_ws, size_t ws_size,
                              hipStream_t stream) {
    const float* x = (const float*)d_in[0];
    const int* edge_index = (const int*)d_in[1];

    int E = in_sizes[1] / 2;
    const int* row = edge_index;      // edge_index[0]
    const int* col = edge_index + E;  // edge_index[1]
    int N = in_sizes[0] / D_FEAT;

    float* out = (float*)d_out;

    int nb = (N + BNODES - 1) / BNODES;  // 782 buckets for N=100000

    // ws layout (ints): cnt[nb] | offs[nb] | fill[nb] | packed[E]
    int* cnt  = (int*)d_ws;
    int* offs = cnt + nb;
    int* fill = offs + nb;
    unsigned* packed = (unsigned*)(fill + nb);

    // zero counters each call (harness does not re-poison)
    hipMemsetAsync(cnt, 0, (size_t)nb * sizeof(int), stream);
    hipMemsetAsync(fill, 0, (size_t)nb * sizeof(int), stream);

    int block = 256;
    size_t hist_lds = (size_t)nb * sizeof(int);
    hist_kernel<<<256, block, hist_lds, stream>>>(row, cnt, E, nb);
    scan_kernel<<<1, NB_MAX, 0, stream>>>(cnt, offs, nb);
    bin_kernel<<<(E + block - 1) / block, block, 0, stream>>>(row, col, offs, fill, packed, E);
    phase2_kernel<<<nb, block, 0, stream>>>(x, packed, offs, cnt, out, N);
}

// Round 4
// 399.748 us; speedup vs baseline: 2.2165x; 2.2165x over previous
//
#include <hip/hip_runtime.h>

#define D_FEAT 32
#define BNODES 128            // nodes per coarse bucket
#define LOG_BN 7
#define NB_MAX 1024           // >= n_buckets (782)
#define CHUNK 8192            // edges per binning block

// ---- pass A: per-block LDS histogram, one global atomic per bucket ----
__global__ void __launch_bounds__(256) countA_kernel(const int* __restrict__ row,
                                                     int* __restrict__ cnt,
                                                     int E, int nb) {
    __shared__ int hist[NB_MAX];
    int t = threadIdx.x;
    for (int i = t; i < nb; i += 256) hist[i] = 0;
    __syncthreads();
    int s = blockIdx.x * CHUNK;
    int e_end = min(E, s + CHUNK);
    for (int e = s + t; e < e_end; e += 256)
        atomicAdd(&hist[row[e] >> LOG_BN], 1);
    __syncthreads();
    for (int i = t; i < nb; i += 256) {
        int h = hist[i];
        if (h) atomicAdd(&cnt[i], h);
    }
}

// ---- exclusive scan of nb (<=1024) counters, single block ----
__global__ void scan_kernel(const int* __restrict__ cnt, int* __restrict__ offs, int nb) {
    __shared__ int sh[NB_MAX];
    int t = threadIdx.x;
    int v0 = (t < nb) ? cnt[t] : 0;
    sh[t] = v0;
    __syncthreads();
    for (int off = 1; off < NB_MAX; off <<= 1) {
        int v = (t >= off) ? sh[t - off] : 0;
        __syncthreads();
        sh[t] += v;
        __syncthreads();
    }
    if (t < nb) offs[t] = sh[t] - v0;  // exclusive prefix
}

// ---- pass B: re-histogram chunk, reserve ranges (1 global atomic per
//      (block,bucket)), assign slots from LDS countdown, emit packed ----
__global__ void __launch_bounds__(256) binB_kernel(const int* __restrict__ row,
                                                   const int* __restrict__ col,
                                                   const int* __restrict__ offs,
                                                   int* __restrict__ gfill,
                                                   unsigned* __restrict__ packed,
                                                   int E, int nb) {
    __shared__ int hist[NB_MAX];
    __shared__ int base[NB_MAX];
    int t = threadIdx.x;
    for (int i = t; i < nb; i += 256) hist[i] = 0;
    __syncthreads();
    int s = blockIdx.x * CHUNK;
    int e_end = min(E, s + CHUNK);
    for (int e = s + t; e < e_end; e += 256)
        atomicAdd(&hist[row[e] >> LOG_BN], 1);
    __syncthreads();
    for (int i = t; i < nb; i += 256) {
        int h = hist[i];
        base[i] = h ? (offs[i] + atomicAdd(&gfill[i], h)) : 0;
    }
    __syncthreads();
    for (int e = s + t; e < e_end; e += 256) {
        int r = row[e];
        int c = col[e];
        int b = r >> LOG_BN;
        int slot = base[b] + atomicAdd(&hist[b], -1) - 1;
        packed[slot] = ((unsigned)(r & (BNODES - 1)) << 17) | (unsigned)c;
    }
}

// ---- per-bucket LDS-accumulated mean ----
__global__ void __launch_bounds__(256) phase2_kernel(const float* __restrict__ x,
                                                     const unsigned* __restrict__ packed,
                                                     const int* __restrict__ offs,
                                                     const int* __restrict__ cnt,
                                                     float* __restrict__ out, int N) {
    __shared__ __align__(16) float acc[BNODES * D_FEAT];  // 16 KB
    __shared__ int degl[BNODES];
    int t = threadIdx.x;
    for (int i = t; i < BNODES * D_FEAT; i += 256) acc[i] = 0.f;
    for (int i = t; i < BNODES; i += 256) degl[i] = 0;
    __syncthreads();

    int b = blockIdx.x;
    int s = offs[b];
    int n = cnt[b];
    int end = s + n;
    int d = t & 31;   // feature lane
    int g = t >> 5;   // edge subgroup 0..7

    int e = s + g;
    for (; e + 24 < end; e += 32) {
        unsigned p0 = packed[e];
        unsigned p1 = packed[e + 8];
        unsigned p2 = packed[e + 16];
        unsigned p3 = packed[e + 24];
        float v0 = x[(p0 & 0x1FFFFu) * D_FEAT + d];
        float v1 = x[(p1 & 0x1FFFFu) * D_FEAT + d];
        float v2 = x[(p2 & 0x1FFFFu) * D_FEAT + d];
        float v3 = x[(p3 & 0x1FFFFu) * D_FEAT + d];
        atomicAdd(&acc[(p0 >> 17) * D_FEAT + d], v0);
        atomicAdd(&acc[(p1 >> 17) * D_FEAT + d], v1);
        atomicAdd(&acc[(p2 >> 17) * D_FEAT + d], v2);
        atomicAdd(&acc[(p3 >> 17) * D_FEAT + d], v3);
        if (d == 0) {
            atomicAdd(&degl[p0 >> 17], 1);
            atomicAdd(&degl[p1 >> 17], 1);
            atomicAdd(&degl[p2 >> 17], 1);
            atomicAdd(&degl[p3 >> 17], 1);
        }
    }
    for (; e < end; e += 8) {
        unsigned p = packed[e];
        float v = x[(p & 0x1FFFFu) * D_FEAT + d];
        atomicAdd(&acc[(p >> 17) * D_FEAT + d], v);
        if (d == 0) atomicAdd(&degl[p >> 17], 1);
    }
    __syncthreads();

    // write this bucket's slab (float4), divided by degree
    int base_node = b * BNODES;
    int nodes_here = min(BNODES, N - base_node);
    const float4* acc4 = (const float4*)acc;
    float4* out4 = (float4*)(out + (size_t)base_node * D_FEAT);
    for (int i = t; i < nodes_here * 8; i += 256) {
        float inv = 1.0f / fmaxf((float)degl[i >> 3], 1.0f);
        float4 v = acc4[i];
        v.x *= inv; v.y *= inv; v.z *= inv; v.w *= inv;
        out4[i] = v;
    }
}

// ---------------- launch ----------------

extern "C" void kernel_launch(void* const* d_in, const int* in_sizes, int n_in,
                              void* d_out, int out_size, void* d_ws, size_t ws_size,
                              hipStream_t stream) {
    const float* x = (const float*)d_in[0];
    const int* edge_index = (const int*)d_in[1];

    int E = in_sizes[1] / 2;
    const int* row = edge_index;      // edge_index[0]
    const int* col = edge_index + E;  // edge_index[1]
    int N = in_sizes[0] / D_FEAT;

    float* out = (float*)d_out;

    int nb = (N + BNODES - 1) / BNODES;  // 782 buckets

    // ws layout (ints): cnt[nb] | offs[nb] | gfill[nb] | packed[E]
    int* cnt   = (int*)d_ws;
    int* offs  = cnt + nb;
    int* gfill = offs + nb;
    unsigned* packed = (unsigned*)(gfill + nb);

    // zero counters each call (harness does not re-poison)
    hipMemsetAsync(cnt, 0, (size_t)nb * sizeof(int), stream);
    hipMemsetAsync(gfill, 0, (size_t)nb * sizeof(int), stream);

    int nblk = (E + CHUNK - 1) / CHUNK;  // 196
    countA_kernel<<<nblk, 256, 0, stream>>>(row, cnt, E, nb);
    scan_kernel<<<1, NB_MAX, 0, stream>>>(cnt, offs, nb);
    binB_kernel<<<nblk, 256, 0, stream>>>(row, col, offs, gfill, packed, E, nb);
    phase2_kernel<<<nb, 256, 0, stream>>>(x, packed, offs, cnt, out, N);
}

// Round 5
// 348.318 us; speedup vs baseline: 2.5438x; 1.1477x over previous
//
#include <hip/hip_runtime.h>

#define D_FEAT 32
#define BNODES 32             // nodes per coarse bucket
#define LOG_BN 5
#define NB_CAP 4096           // max buckets the scan supports (1024 thr x 4)
#define CHUNK 8192            // edges per binning block

// ---- pass A: per-block LDS histogram, one global atomic per bucket ----
__global__ void __launch_bounds__(256) countA_kernel(const int* __restrict__ row,
                                                     int* __restrict__ cnt,
                                                     int E, int nb) {
    extern __shared__ int hist[];
    int t = threadIdx.x;
    for (int i = t; i < nb; i += 256) hist[i] = 0;
    __syncthreads();
    int s = blockIdx.x * CHUNK;
    int e_end = min(E, s + CHUNK);
    for (int e = s + t; e < e_end; e += 256)
        atomicAdd(&hist[row[e] >> LOG_BN], 1);
    __syncthreads();
    for (int i = t; i < nb; i += 256) {
        int h = hist[i];
        if (h) atomicAdd(&cnt[i], h);
    }
}

// ---- exclusive scan of nb (<=4096) counters, single 1024-thread block ----
__global__ void __launch_bounds__(1024) scan_kernel(const int* __restrict__ cnt,
                                                    int* __restrict__ offs, int nb) {
    __shared__ int sh[1024];
    int t = threadIdx.x;
    int base = t * 4;
    int v0 = (base + 0 < nb) ? cnt[base + 0] : 0;
    int v1 = (base + 1 < nb) ? cnt[base + 1] : 0;
    int v2 = (base + 2 < nb) ? cnt[base + 2] : 0;
    int v3 = (base + 3 < nb) ? cnt[base + 3] : 0;
    int s = v0 + v1 + v2 + v3;
    sh[t] = s;
    __syncthreads();
    for (int off = 1; off < 1024; off <<= 1) {
        int v = (t >= off) ? sh[t - off] : 0;
        __syncthreads();
        sh[t] += v;
        __syncthreads();
    }
    int p = sh[t] - s;  // exclusive prefix of this thread's chunk
    if (base + 0 < nb) offs[base + 0] = p; p += v0;
    if (base + 1 < nb) offs[base + 1] = p; p += v1;
    if (base + 2 < nb) offs[base + 2] = p; p += v2;
    if (base + 3 < nb) offs[base + 3] = p;
}

// ---- pass B: re-histogram chunk, reserve ranges, emit packed ----
__global__ void __launch_bounds__(256) binB_kernel(const int* __restrict__ row,
                                                   const int* __restrict__ col,
                                                   const int* __restrict__ offs,
                                                   int* __restrict__ gfill,
                                                   unsigned* __restrict__ packed,
                                                   int E, int nb) {
    extern __shared__ int shmem[];
    int* hist = shmem;
    int* base = shmem + nb;
    int t = threadIdx.x;
    for (int i = t; i < nb; i += 256) hist[i] = 0;
    __syncthreads();
    int s = blockIdx.x * CHUNK;
    int e_end = min(E, s + CHUNK);
    for (int e = s + t; e < e_end; e += 256)
        atomicAdd(&hist[row[e] >> LOG_BN], 1);
    __syncthreads();
    for (int i = t; i < nb; i += 256) {
        int h = hist[i];
        base[i] = h ? (offs[i] + atomicAdd(&gfill[i], h)) : 0;
    }
    __syncthreads();
    for (int e = s + t; e < e_end; e += 256) {
        int r = row[e];
        int c = col[e];
        int b = r >> LOG_BN;
        int slot = base[b] + atomicAdd(&hist[b], -1) - 1;
        packed[slot] = ((unsigned)(r & (BNODES - 1)) << 17) | (unsigned)c;
    }
}

// ---- per-bucket LDS-accumulated mean, 8-deep gather pipeline ----
__global__ void __launch_bounds__(256) phase2_kernel(const float* __restrict__ x,
                                                     const unsigned* __restrict__ packed,
                                                     const int* __restrict__ offs,
                                                     const int* __restrict__ cnt,
                                                     float* __restrict__ out, int N) {
    __shared__ __align__(16) float acc[BNODES * D_FEAT];  // 4 KB
    __shared__ int degl[BNODES];
    int t = threadIdx.x;
    for (int i = t; i < BNODES * D_FEAT; i += 256) acc[i] = 0.f;
    if (t < BNODES) degl[t] = 0;
    __syncthreads();

    int b = blockIdx.x;
    int s = offs[b];
    int n = cnt[b];
    int end = s + n;
    int d = t & 31;   // feature lane
    int g = t >> 5;   // edge subgroup 0..7

    int e = s + g;
    // 8 independent gathers in flight per thread
    for (; e + 56 < end; e += 64) {
        unsigned p[8];
        float v[8];
        #pragma unroll
        for (int u = 0; u < 8; ++u) p[u] = packed[e + 8 * u];
        #pragma unroll
        for (int u = 0; u < 8; ++u) v[u] = x[(p[u] & 0x1FFFFu) * D_FEAT + d];
        #pragma unroll
        for (int u = 0; u < 8; ++u) {
            atomicAdd(&acc[(p[u] >> 17) * D_FEAT + d], v[u]);
            if (d == 0) atomicAdd(&degl[p[u] >> 17], 1);
        }
    }
    for (; e < end; e += 8) {
        unsigned p = packed[e];
        float v = x[(p & 0x1FFFFu) * D_FEAT + d];
        atomicAdd(&acc[(p >> 17) * D_FEAT + d], v);
        if (d == 0) atomicAdd(&degl[p >> 17], 1);
    }
    __syncthreads();

    // write this bucket's slab (float4), divided by degree
    int base_node = b * BNODES;
    int nodes_here = min(BNODES, N - base_node);
    const float4* acc4 = (const float4*)acc;
    float4* out4 = (float4*)(out + (size_t)base_node * D_FEAT);
    for (int i = t; i < nodes_here * 8; i += 256) {
        float inv = 1.0f / fmaxf((float)degl[i >> 3], 1.0f);
        float4 v = acc4[i];
        v.x *= inv; v.y *= inv; v.z *= inv; v.w *= inv;
        out4[i] = v;
    }
}

// ---------------- launch ----------------

extern "C" void kernel_launch(void* const* d_in, const int* in_sizes, int n_in,
                              void* d_out, int out_size, void* d_ws, size_t ws_size,
                              hipStream_t stream) {
    const float* x = (const float*)d_in[0];
    const int* edge_index = (const int*)d_in[1];

    int E = in_sizes[1] / 2;
    const int* row = edge_index;      // edge_index[0]
    const int* col = edge_index + E;  // edge_index[1]
    int N = in_sizes[0] / D_FEAT;

    float* out = (float*)d_out;

    int nb = (N + BNODES - 1) / BNODES;  // 3125 buckets
    if (nb > NB_CAP) nb = NB_CAP;        // (not hit for this problem)

    // ws layout (ints): cnt[nb] | offs[nb] | gfill[nb] | packed[E]
    int* cnt   = (int*)d_ws;
    int* offs  = cnt + nb;
    int* gfill = offs + nb;
    unsigned* packed = (unsigned*)(gfill + nb);

    // zero counters each call (harness does not re-poison)
    hipMemsetAsync(cnt, 0, (size_t)nb * sizeof(int), stream);
    hipMemsetAsync(gfill, 0, (size_t)nb * sizeof(int), stream);

    int nblk = (E + CHUNK - 1) / CHUNK;  // 196
    size_t lds1 = (size_t)nb * sizeof(int);
    size_t lds2 = (size_t)2 * nb * sizeof(int);
    countA_kernel<<<nblk, 256, lds1, stream>>>(row, cnt, E, nb);
    scan_kernel<<<1, 1024, 0, stream>>>(cnt, offs, nb);
    binB_kernel<<<nblk, 256, lds2, stream>>>(row, col, offs, gfill, packed, E, nb);
    phase2_kernel<<<nb, 256, 0, stream>>>(x, packed, offs, cnt, out, N);
}

// Round 6
// 342.731 us; speedup vs baseline: 2.5853x; 1.0163x over previous
//
#include <hip/hip_runtime.h>

#define D_FEAT 32
#define BNODES 32             // nodes per coarse bucket
#define LOG_BN 5
#define NB_CAP 4096           // max buckets the scan supports (1024 thr x 4)
#define CHUNK 8192            // edges per binning block
#define ACC_STRIDE 33         // +1-padded LDS row stride (floats)

// ---- pass A: per-block LDS histogram, one global atomic per bucket ----
__global__ void __launch_bounds__(256) countA_kernel(const int* __restrict__ row,
                                                     int* __restrict__ cnt,
                                                     int E, int nb) {
    extern __shared__ int hist[];
    int t = threadIdx.x;
    for (int i = t; i < nb; i += 256) hist[i] = 0;
    __syncthreads();
    int s = blockIdx.x * CHUNK;
    int e_end = min(E, s + CHUNK);
    // vectorized int4 path over full quads
    int e = s + t * 4;
    for (; e + 3 < e_end; e += 1024) {
        int4 r4 = *(const int4*)&row[e];
        atomicAdd(&hist[r4.x >> LOG_BN], 1);
        atomicAdd(&hist[r4.y >> LOG_BN], 1);
        atomicAdd(&hist[r4.z >> LOG_BN], 1);
        atomicAdd(&hist[r4.w >> LOG_BN], 1);
    }
    // scalar tail
    for (int e2 = e; e2 < e_end; ++e2)
        atomicAdd(&hist[row[e2] >> LOG_BN], 1);
    __syncthreads();
    for (int i = t; i < nb; i += 256) {
        int h = hist[i];
        if (h) atomicAdd(&cnt[i], h);
    }
}

// ---- exclusive scan of nb (<=4096) counters, single 1024-thread block ----
__global__ void __launch_bounds__(1024) scan_kernel(const int* __restrict__ cnt,
                                                    int* __restrict__ offs, int nb) {
    __shared__ int sh[1024];
    int t = threadIdx.x;
    int base = t * 4;
    int v0 = (base + 0 < nb) ? cnt[base + 0] : 0;
    int v1 = (base + 1 < nb) ? cnt[base + 1] : 0;
    int v2 = (base + 2 < nb) ? cnt[base + 2] : 0;
    int v3 = (base + 3 < nb) ? cnt[base + 3] : 0;
    int s = v0 + v1 + v2 + v3;
    sh[t] = s;
    __syncthreads();
    for (int off = 1; off < 1024; off <<= 1) {
        int v = (t >= off) ? sh[t - off] : 0;
        __syncthreads();
        sh[t] += v;
        __syncthreads();
    }
    int p = sh[t] - s;  // exclusive prefix of this thread's chunk
    if (base + 0 < nb) offs[base + 0] = p; p += v0;
    if (base + 1 < nb) offs[base + 1] = p; p += v1;
    if (base + 2 < nb) offs[base + 2] = p; p += v2;
    if (base + 3 < nb) offs[base + 3] = p;
}

// ---- pass B: re-histogram chunk, reserve ranges, emit packed ----
__global__ void __launch_bounds__(256) binB_kernel(const int* __restrict__ row,
                                                   const int* __restrict__ col,
                                                   const int* __restrict__ offs,
                                                   int* __restrict__ gfill,
                                                   unsigned* __restrict__ packed,
                                                   int E, int nb) {
    extern __shared__ int shmem[];
    int* hist = shmem;
    int* base = shmem + nb;
    int t = threadIdx.x;
    for (int i = t; i < nb; i += 256) hist[i] = 0;
    __syncthreads();
    int s = blockIdx.x * CHUNK;
    int e_end = min(E, s + CHUNK);
    for (int e = s + t; e < e_end; e += 256)
        atomicAdd(&hist[row[e] >> LOG_BN], 1);
    __syncthreads();
    for (int i = t; i < nb; i += 256) {
        int h = hist[i];
        base[i] = h ? (offs[i] + atomicAdd(&gfill[i], h)) : 0;
    }
    __syncthreads();
    for (int e = s + t; e < e_end; e += 256) {
        int r = row[e];
        int c = col[e];
        int b = r >> LOG_BN;
        int slot = base[b] + atomicAdd(&hist[b], -1) - 1;
        packed[slot] = ((unsigned)(r & (BNODES - 1)) << 17) | (unsigned)c;
    }
}

// ---- per-bucket LDS-accumulated mean: 8 lanes per edge, float4 per lane ----
__global__ void __launch_bounds__(256) phase2_kernel(const float* __restrict__ x,
                                                     const unsigned* __restrict__ packed,
                                                     const int* __restrict__ offs,
                                                     const int* __restrict__ cnt,
                                                     float* __restrict__ out, int N) {
    __shared__ float acc[BNODES * ACC_STRIDE];  // 4224 B, +1-padded rows
    __shared__ int degl[BNODES];
    int t = threadIdx.x;
    for (int i = t; i < BNODES * ACC_STRIDE; i += 256) acc[i] = 0.f;
    if (t < BNODES) degl[t] = 0;
    __syncthreads();

    int b = blockIdx.x;
    int s = offs[b];
    int n = cnt[b];
    int end = s + n;
    int oct = t >> 3;   // edge slot within a 32-edge sweep
    int j = t & 7;      // quarter-row (float4) lane
    const float4* x4 = (const float4*)x;

    int e = s + oct;
    // 4-deep pipeline: 128 edges per block-iteration, all loads before all uses
    for (; e + 96 < end; e += 128) {
        unsigned p0 = packed[e];
        unsigned p1 = packed[e + 32];
        unsigned p2 = packed[e + 64];
        unsigned p3 = packed[e + 96];
        float4 v0 = x4[(p0 & 0x1FFFFu) * 8 + j];
        float4 v1 = x4[(p1 & 0x1FFFFu) * 8 + j];
        float4 v2 = x4[(p2 & 0x1FFFFu) * 8 + j];
        float4 v3 = x4[(p3 & 0x1FFFFu) * 8 + j];
        int r0 = p0 >> 17, r1 = p1 >> 17, r2 = p2 >> 17, r3 = p3 >> 17;
        int a0 = r0 * ACC_STRIDE + 4 * j;
        int a1 = r1 * ACC_STRIDE + 4 * j;
        int a2 = r2 * ACC_STRIDE + 4 * j;
        int a3 = r3 * ACC_STRIDE + 4 * j;
        atomicAdd(&acc[a0 + 0], v0.x); atomicAdd(&acc[a0 + 1], v0.y);
        atomicAdd(&acc[a0 + 2], v0.z); atomicAdd(&acc[a0 + 3], v0.w);
        atomicAdd(&acc[a1 + 0], v1.x); atomicAdd(&acc[a1 + 1], v1.y);
        atomicAdd(&acc[a1 + 2], v1.z); atomicAdd(&acc[a1 + 3], v1.w);
        atomicAdd(&acc[a2 + 0], v2.x); atomicAdd(&acc[a2 + 1], v2.y);
        atomicAdd(&acc[a2 + 2], v2.z); atomicAdd(&acc[a2 + 3], v2.w);
        atomicAdd(&acc[a3 + 0], v3.x); atomicAdd(&acc[a3 + 1], v3.y);
        atomicAdd(&acc[a3 + 2], v3.z); atomicAdd(&acc[a3 + 3], v3.w);
        if (j == 0) {
            atomicAdd(&degl[r0], 1);
            atomicAdd(&degl[r1], 1);
            atomicAdd(&degl[r2], 1);
            atomicAdd(&degl[r3], 1);
        }
    }
    // remainder (at most 3 sweeps per thread)
    for (; e < end; e += 32) {
        unsigned p = packed[e];
        float4 v = x4[(p & 0x1FFFFu) * 8 + j];
        int r = p >> 17;
        int a = r * ACC_STRIDE + 4 * j;
        atomicAdd(&acc[a + 0], v.x); atomicAdd(&acc[a + 1], v.y);
        atomicAdd(&acc[a + 2], v.z); atomicAdd(&acc[a + 3], v.w);
        if (j == 0) atomicAdd(&degl[r], 1);
    }
    __syncthreads();

    // write out: thread t -> node t>>3, quad t&7 (coalesced float4 stores)
    int node = oct;
    int gnode = b * BNODES + node;
    if (gnode < N) {
        float invd = 1.0f / fmaxf((float)degl[node], 1.0f);
        int a = node * ACC_STRIDE + 4 * j;
        float4 v;
        v.x = acc[a + 0] * invd;
        v.y = acc[a + 1] * invd;
        v.z = acc[a + 2] * invd;
        v.w = acc[a + 3] * invd;
        ((float4*)out)[(size_t)gnode * 8 + j] = v;
    }
}

// ---------------- launch ----------------

extern "C" void kernel_launch(void* const* d_in, const int* in_sizes, int n_in,
                              void* d_out, int out_size, void* d_ws, size_t ws_size,
                              hipStream_t stream) {
    const float* x = (const float*)d_in[0];
    const int* edge_index = (const int*)d_in[1];

    int E = in_sizes[1] / 2;
    const int* row = edge_index;      // edge_index[0]
    const int* col = edge_index + E;  // edge_index[1]
    int N = in_sizes[0] / D_FEAT;

    float* out = (float*)d_out;

    int nb = (N + BNODES - 1) / BNODES;  // 3125 buckets
    if (nb > NB_CAP) nb = NB_CAP;

    // ws layout (ints): cnt[nb] | offs[nb] | gfill[nb] | packed[E]
    int* cnt   = (int*)d_ws;
    int* offs  = cnt + nb;
    int* gfill = offs + nb;
    unsigned* packed = (unsigned*)(gfill + nb);

    // zero counters each call (harness does not re-poison)
    hipMemsetAsync(cnt, 0, (size_t)nb * sizeof(int), stream);
    hipMemsetAsync(gfill, 0, (size_t)nb * sizeof(int), stream);

    int nblk = (E + CHUNK - 1) / CHUNK;  // 196
    size_t lds1 = (size_t)nb * sizeof(int);
    size_t lds2 = (size_t)2 * nb * sizeof(int);
    countA_kernel<<<nblk, 256, lds1, stream>>>(row, cnt, E, nb);
    scan_kernel<<<1, 1024, 0, stream>>>(cnt, offs, nb);
    binB_kernel<<<nblk, 256, lds2, stream>>>(row, col, offs, gfill, packed, E, nb);
    phase2_kernel<<<nb, 256, 0, stream>>>(x, packed, offs, cnt, out, N);
}

// Round 7
// 91.991 us; speedup vs baseline: 9.6320x; 3.7257x over previous
//
#include <hip/hip_runtime.h>

#define D_FEAT 32
#define BNODES 32             // nodes per coarse bucket
#define LOG_BN 5
#define NB_CAP 4096           // max buckets the scan supports (1024 thr x 4)
#define CHUNK 8192            // edges per binning block
#define ECHUNK 1024           // edges per in-block sort chunk (phase 2)
#define CMASK 0x1FFFFu        // low 17 bits = col

// ---- pass A: per-block LDS histogram, one global atomic per bucket ----
__global__ void __launch_bounds__(256) countA_kernel(const int* __restrict__ row,
                                                     int* __restrict__ cnt,
                                                     int E, int nb) {
    extern __shared__ int hist[];
    int t = threadIdx.x;
    for (int i = t; i < nb; i += 256) hist[i] = 0;
    __syncthreads();
    int s = blockIdx.x * CHUNK;
    int e_end = min(E, s + CHUNK);
    int e = s + t * 4;
    for (; e + 3 < e_end; e += 1024) {
        int4 r4 = *(const int4*)&row[e];
        atomicAdd(&hist[r4.x >> LOG_BN], 1);
        atomicAdd(&hist[r4.y >> LOG_BN], 1);
        atomicAdd(&hist[r4.z >> LOG_BN], 1);
        atomicAdd(&hist[r4.w >> LOG_BN], 1);
    }
    for (int e2 = e; e2 < e_end; ++e2)
        atomicAdd(&hist[row[e2] >> LOG_BN], 1);
    __syncthreads();
    for (int i = t; i < nb; i += 256) {
        int h = hist[i];
        if (h) atomicAdd(&cnt[i], h);
    }
}

// ---- exclusive scan of nb (<=4096) counters, single 1024-thread block ----
__global__ void __launch_bounds__(1024) scan_kernel(const int* __restrict__ cnt,
                                                    int* __restrict__ offs, int nb) {
    __shared__ int sh[1024];
    int t = threadIdx.x;
    int base = t * 4;
    int v0 = (base + 0 < nb) ? cnt[base + 0] : 0;
    int v1 = (base + 1 < nb) ? cnt[base + 1] : 0;
    int v2 = (base + 2 < nb) ? cnt[base + 2] : 0;
    int v3 = (base + 3 < nb) ? cnt[base + 3] : 0;
    int s = v0 + v1 + v2 + v3;
    sh[t] = s;
    __syncthreads();
    for (int off = 1; off < 1024; off <<= 1) {
        int v = (t >= off) ? sh[t - off] : 0;
        __syncthreads();
        sh[t] += v;
        __syncthreads();
    }
    int p = sh[t] - s;
    if (base + 0 < nb) offs[base + 0] = p; p += v0;
    if (base + 1 < nb) offs[base + 1] = p; p += v1;
    if (base + 2 < nb) offs[base + 2] = p; p += v2;
    if (base + 3 < nb) offs[base + 3] = p;
}

// ---- pass B: re-histogram chunk, reserve ranges, emit packed ----
__global__ void __launch_bounds__(256) binB_kernel(const int* __restrict__ row,
                                                   const int* __restrict__ col,
                                                   const int* __restrict__ offs,
                                                   int* __restrict__ gfill,
                                                   unsigned* __restrict__ packed,
                                                   int E, int nb) {
    extern __shared__ int shmem[];
    int* hist = shmem;
    int* base = shmem + nb;
    int t = threadIdx.x;
    for (int i = t; i < nb; i += 256) hist[i] = 0;
    __syncthreads();
    int s = blockIdx.x * CHUNK;
    int e_end = min(E, s + CHUNK);
    for (int e = s + t; e < e_end; e += 256)
        atomicAdd(&hist[row[e] >> LOG_BN], 1);
    __syncthreads();
    for (int i = t; i < nb; i += 256) {
        int h = hist[i];
        base[i] = h ? (offs[i] + atomicAdd(&gfill[i], h)) : 0;
    }
    __syncthreads();
    for (int e = s + t; e < e_end; e += 256) {
        int r = row[e];
        int c = col[e];
        int b = r >> LOG_BN;
        int slot = base[b] + atomicAdd(&hist[b], -1) - 1;
        packed[slot] = ((unsigned)(r & (BNODES - 1)) << 17) | (unsigned)c;
    }
}

// ---- phase 2: in-block counting sort + register-accumulated reduce ----
// Thread t owns (node = t>>3, quad j = t&7). No LDS atomics in the gather loop.
__global__ void __launch_bounds__(256) phase2_kernel(const float* __restrict__ x,
                                                     const unsigned* __restrict__ packed,
                                                     const int* __restrict__ offs,
                                                     const int* __restrict__ cnt,
                                                     float* __restrict__ out, int N) {
    __shared__ unsigned scol[ECHUNK];   // 4 KB: row-sorted packed entries
    __shared__ int hist[BNODES];
    __shared__ int hoff[BNODES];
    int t = threadIdx.x;
    int b = blockIdx.x;
    int s = offs[b];
    int n = cnt[b];
    int node = t >> 3;
    int j = t & 7;
    const float4* x4 = (const float4*)x;

    float4 acc = make_float4(0.f, 0.f, 0.f, 0.f);
    int mydeg = 0;

    for (int cs = 0; cs < n; cs += ECHUNK) {
        int m = min(ECHUNK, n - cs);
        if (t < BNODES) hist[t] = 0;
        __syncthreads();
        // histogram local rows of this chunk
        for (int i = t; i < m; i += 256)
            atomicAdd(&hist[packed[s + cs + i] >> 17], 1);
        __syncthreads();
        // exclusive scan of 32 counters (wave 0, shfl)
        if (t < 64) {
            int v = (t < BNODES) ? hist[t] : 0;
            int sum = v;
            #pragma unroll
            for (int off = 1; off < BNODES; off <<= 1) {
                int w = __shfl_up(sum, off);
                if (t >= off) sum += w;
            }
            if (t < BNODES) hoff[t] = sum - v;
        }
        __syncthreads();
        int mcount = hist[node];
        int mbase = hoff[node];
        mydeg += mcount;
        __syncthreads();
        // scatter into scol, countdown slot assignment (destroys hist)
        for (int i = t; i < m; i += 256) {
            unsigned p = packed[s + cs + i];
            int r = p >> 17;
            int slot = hoff[r] + atomicAdd(&hist[r], -1) - 1;
            scol[slot] = p;
        }
        __syncthreads();
        // register-accumulated reduce over my node's contiguous sublist
        int i = 0;
        for (; i + 3 < mcount; i += 4) {
            unsigned c0 = scol[mbase + i + 0] & CMASK;
            unsigned c1 = scol[mbase + i + 1] & CMASK;
            unsigned c2 = scol[mbase + i + 2] & CMASK;
            unsigned c3 = scol[mbase + i + 3] & CMASK;
            float4 v0 = x4[c0 * 8 + j];
            float4 v1 = x4[c1 * 8 + j];
            float4 v2 = x4[c2 * 8 + j];
            float4 v3 = x4[c3 * 8 + j];
            acc.x += v0.x; acc.y += v0.y; acc.z += v0.z; acc.w += v0.w;
            acc.x += v1.x; acc.y += v1.y; acc.z += v1.z; acc.w += v1.w;
            acc.x += v2.x; acc.y += v2.y; acc.z += v2.z; acc.w += v2.w;
            acc.x += v3.x; acc.y += v3.y; acc.z += v3.z; acc.w += v3.w;
        }
        for (; i < mcount; ++i) {
            unsigned c = scol[mbase + i] & CMASK;
            float4 v = x4[c * 8 + j];
            acc.x += v.x; acc.y += v.y; acc.z += v.z; acc.w += v.w;
        }
        __syncthreads();  // scol consumed before next chunk overwrites
    }

    int gnode = b * BNODES + node;
    if (gnode < N) {
        float invd = 1.0f / fmaxf((float)mydeg, 1.0f);
        float4 v;
        v.x = acc.x * invd; v.y = acc.y * invd;
        v.z = acc.z * invd; v.w = acc.w * invd;
        ((float4*)out)[(size_t)gnode * 8 + j] = v;
    }
}

// ---------------- launch ----------------

extern "C" void kernel_launch(void* const* d_in, const int* in_sizes, int n_in,
                              void* d_out, int out_size, void* d_ws, size_t ws_size,
                              hipStream_t stream) {
    const float* x = (const float*)d_in[0];
    const int* edge_index = (const int*)d_in[1];

    int E = in_sizes[1] / 2;
    const int* row = edge_index;      // edge_index[0]
    const int* col = edge_index + E;  // edge_index[1]
    int N = in_sizes[0] / D_FEAT;

    float* out = (float*)d_out;

    int nb = (N + BNODES - 1) / BNODES;  // 3125 buckets
    if (nb > NB_CAP) nb = NB_CAP;

    // ws layout (ints): cnt[nb] | offs[nb] | gfill[nb] | packed[E]
    int* cnt   = (int*)d_ws;
    int* offs  = cnt + nb;
    int* gfill = offs + nb;
    unsigned* packed = (unsigned*)(gfill + nb);

    hipMemsetAsync(cnt, 0, (size_t)nb * sizeof(int), stream);
    hipMemsetAsync(gfill, 0, (size_t)nb * sizeof(int), stream);

    int nblk = (E + CHUNK - 1) / CHUNK;  // 196
    size_t lds1 = (size_t)nb * sizeof(int);
    size_t lds2 = (size_t)2 * nb * sizeof(int);
    countA_kernel<<<nblk, 256, lds1, stream>>>(row, cnt, E, nb);
    scan_kernel<<<1, 1024, 0, stream>>>(cnt, offs, nb);
    binB_kernel<<<nblk, 256, lds2, stream>>>(row, col, offs, gfill, packed, E, nb);
    phase2_kernel<<<nb, 256, 0, stream>>>(x, packed, offs, cnt, out, N);
}

// Round 8
// 78.155 us; speedup vs baseline: 11.3371x; 1.1770x over previous
//
#include <hip/hip_runtime.h>

#define D_FEAT 32
#define BNODES 32             // nodes per coarse bucket
#define LOG_BN 5
#define NB_CAP 4096           // max buckets the scan supports (1024 thr x 4)
#define CHUNK 8192            // edges per binning block
#define BIG 1024              // threads for binning kernels
#define ECHUNK 1024           // edges per in-block sort chunk (phase 2)
#define CMASK 0x1FFFFu        // low 17 bits = col

// ---- pass A: per-block LDS histogram, one global atomic per bucket ----
__global__ void __launch_bounds__(BIG) countA_kernel(const int* __restrict__ row,
                                                     int* __restrict__ cnt,
                                                     int E, int nb) {
    extern __shared__ int hist[];
    int t = threadIdx.x;
    for (int i = t; i < nb; i += BIG) hist[i] = 0;
    __syncthreads();
    int s = blockIdx.x * CHUNK;
    int e_end = min(E, s + CHUNK);
    int e = s + t * 4;
    for (; e + 3 < e_end; e += BIG * 4) {
        int4 r4 = *(const int4*)&row[e];
        atomicAdd(&hist[r4.x >> LOG_BN], 1);
        atomicAdd(&hist[r4.y >> LOG_BN], 1);
        atomicAdd(&hist[r4.z >> LOG_BN], 1);
        atomicAdd(&hist[r4.w >> LOG_BN], 1);
    }
    for (int e2 = e; e2 < e_end; ++e2)
        atomicAdd(&hist[row[e2] >> LOG_BN], 1);
    __syncthreads();
    for (int i = t; i < nb; i += BIG) {
        int h = hist[i];
        if (h) atomicAdd(&cnt[i], h);
    }
}

// ---- exclusive scan of nb (<=4096) counters, single 1024-thread block ----
__global__ void __launch_bounds__(1024) scan_kernel(const int* __restrict__ cnt,
                                                    int* __restrict__ offs, int nb) {
    __shared__ int sh[1024];
    int t = threadIdx.x;
    int base = t * 4;
    int v0 = (base + 0 < nb) ? cnt[base + 0] : 0;
    int v1 = (base + 1 < nb) ? cnt[base + 1] : 0;
    int v2 = (base + 2 < nb) ? cnt[base + 2] : 0;
    int v3 = (base + 3 < nb) ? cnt[base + 3] : 0;
    int s = v0 + v1 + v2 + v3;
    sh[t] = s;
    __syncthreads();
    for (int off = 1; off < 1024; off <<= 1) {
        int v = (t >= off) ? sh[t - off] : 0;
        __syncthreads();
        sh[t] += v;
        __syncthreads();
    }
    int p = sh[t] - s;
    if (base + 0 < nb) offs[base + 0] = p; p += v0;
    if (base + 1 < nb) offs[base + 1] = p; p += v1;
    if (base + 2 < nb) offs[base + 2] = p; p += v2;
    if (base + 3 < nb) offs[base + 3] = p;
}

// ---- pass B: re-histogram chunk, reserve ranges, emit packed ----
__global__ void __launch_bounds__(BIG) binB_kernel(const int* __restrict__ row,
                                                   const int* __restrict__ col,
                                                   const int* __restrict__ offs,
                                                   int* __restrict__ gfill,
                                                   unsigned* __restrict__ packed,
                                                   int E, int nb) {
    extern __shared__ int shmem[];
    int* hist = shmem;
    int* base = shmem + nb;
    int t = threadIdx.x;
    for (int i = t; i < nb; i += BIG) hist[i] = 0;
    __syncthreads();
    int s = blockIdx.x * CHUNK;
    int e_end = min(E, s + CHUNK);

    // histogram (int4)
    int e = s + t * 4;
    for (; e + 3 < e_end; e += BIG * 4) {
        int4 r4 = *(const int4*)&row[e];
        atomicAdd(&hist[r4.x >> LOG_BN], 1);
        atomicAdd(&hist[r4.y >> LOG_BN], 1);
        atomicAdd(&hist[r4.z >> LOG_BN], 1);
        atomicAdd(&hist[r4.w >> LOG_BN], 1);
    }
    for (int e2 = e; e2 < e_end; ++e2)
        atomicAdd(&hist[row[e2] >> LOG_BN], 1);
    __syncthreads();

    // reserve contiguous ranges: one global atomic per (block,bucket)
    for (int i = t; i < nb; i += BIG) {
        int h = hist[i];
        base[i] = h ? (offs[i] + atomicAdd(&gfill[i], h)) : 0;
    }
    __syncthreads();

    // scatter (int4 on row and col)
    e = s + t * 4;
    for (; e + 3 < e_end; e += BIG * 4) {
        int4 r4 = *(const int4*)&row[e];
        int4 c4 = *(const int4*)&col[e];
        int b, slot;
        b = r4.x >> LOG_BN; slot = base[b] + atomicAdd(&hist[b], -1) - 1;
        packed[slot] = ((unsigned)(r4.x & (BNODES - 1)) << 17) | (unsigned)c4.x;
        b = r4.y >> LOG_BN; slot = base[b] + atomicAdd(&hist[b], -1) - 1;
        packed[slot] = ((unsigned)(r4.y & (BNODES - 1)) << 17) | (unsigned)c4.y;
        b = r4.z >> LOG_BN; slot = base[b] + atomicAdd(&hist[b], -1) - 1;
        packed[slot] = ((unsigned)(r4.z & (BNODES - 1)) << 17) | (unsigned)c4.z;
        b = r4.w >> LOG_BN; slot = base[b] + atomicAdd(&hist[b], -1) - 1;
        packed[slot] = ((unsigned)(r4.w & (BNODES - 1)) << 17) | (unsigned)c4.w;
    }
    for (int e2 = e; e2 < e_end; ++e2) {
        int r = row[e2];
        int c = col[e2];
        int b = r >> LOG_BN;
        int slot = base[b] + atomicAdd(&hist[b], -1) - 1;
        packed[slot] = ((unsigned)(r & (BNODES - 1)) << 17) | (unsigned)c;
    }
}

// ---- phase 2: in-block counting sort + register-accumulated reduce ----
__global__ void __launch_bounds__(256) phase2_kernel(const float* __restrict__ x,
                                                     const unsigned* __restrict__ packed,
                                                     const int* __restrict__ offs,
                                                     const int* __restrict__ cnt,
                                                     float* __restrict__ out, int N) {
    __shared__ unsigned scol[ECHUNK];   // 4 KB: row-sorted packed entries
    __shared__ int hist[BNODES];
    __shared__ int hoff[BNODES];
    int t = threadIdx.x;
    int b = blockIdx.x;
    int s = offs[b];
    int n = cnt[b];
    int node = t >> 3;
    int j = t & 7;
    const float4* x4 = (const float4*)x;

    float4 acc = make_float4(0.f, 0.f, 0.f, 0.f);
    int mydeg = 0;

    for (int cs = 0; cs < n; cs += ECHUNK) {
        int m = min(ECHUNK, n - cs);
        if (t < BNODES) hist[t] = 0;
        __syncthreads();
        for (int i = t; i < m; i += 256)
            atomicAdd(&hist[packed[s + cs + i] >> 17], 1);
        __syncthreads();
        if (t < 64) {
            int v = (t < BNODES) ? hist[t] : 0;
            int sum = v;
            #pragma unroll
            for (int off = 1; off < BNODES; off <<= 1) {
                int w = __shfl_up(sum, off);
                if (t >= off) sum += w;
            }
            if (t < BNODES) hoff[t] = sum - v;
        }
        __syncthreads();
        int mcount = hist[node];
        int mbase = hoff[node];
        mydeg += mcount;
        __syncthreads();
        for (int i = t; i < m; i += 256) {
            unsigned p = packed[s + cs + i];
            int r = p >> 17;
            int slot = hoff[r] + atomicAdd(&hist[r], -1) - 1;
            scol[slot] = p;
        }
        __syncthreads();
        int i = 0;
        for (; i + 3 < mcount; i += 4) {
            unsigned c0 = scol[mbase + i + 0] & CMASK;
            unsigned c1 = scol[mbase + i + 1] & CMASK;
            unsigned c2 = scol[mbase + i + 2] & CMASK;
            unsigned c3 = scol[mbase + i + 3] & CMASK;
            float4 v0 = x4[c0 * 8 + j];
            float4 v1 = x4[c1 * 8 + j];
            float4 v2 = x4[c2 * 8 + j];
            float4 v3 = x4[c3 * 8 + j];
            acc.x += v0.x; acc.y += v0.y; acc.z += v0.z; acc.w += v0.w;
            acc.x += v1.x; acc.y += v1.y; acc.z += v1.z; acc.w += v1.w;
            acc.x += v2.x; acc.y += v2.y; acc.z += v2.z; acc.w += v2.w;
            acc.x += v3.x; acc.y += v3.y; acc.z += v3.z; acc.w += v3.w;
        }
        for (; i < mcount; ++i) {
            unsigned c = scol[mbase + i] & CMASK;
            float4 v = x4[c * 8 + j];
            acc.x += v.x; acc.y += v.y; acc.z += v.z; acc.w += v.w;
        }
        __syncthreads();
    }

    int gnode = b * BNODES + node;
    if (gnode < N) {
        float invd = 1.0f / fmaxf((float)mydeg, 1.0f);
        float4 v;
        v.x = acc.x * invd; v.y = acc.y * invd;
        v.z = acc.z * invd; v.w = acc.w * invd;
        ((float4*)out)[(size_t)gnode * 8 + j] = v;
    }
}

// ---------------- launch ----------------

extern "C" void kernel_launch(void* const* d_in, const int* in_sizes, int n_in,
                              void* d_out, int out_size, void* d_ws, size_t ws_size,
                              hipStream_t stream) {
    const float* x = (const float*)d_in[0];
    const int* edge_index = (const int*)d_in[1];

    int E = in_sizes[1] / 2;
    const int* row = edge_index;      // edge_index[0]
    const int* col = edge_index + E;  // edge_index[1]
    int N = in_sizes[0] / D_FEAT;

    float* out = (float*)d_out;

    int nb = (N + BNODES - 1) / BNODES;  // 3125 buckets
    if (nb > NB_CAP) nb = NB_CAP;

    // ws layout (ints): cnt[nb] | offs[nb] | gfill[nb] | packed[E]
    int* cnt   = (int*)d_ws;
    int* offs  = cnt + nb;
    int* gfill = offs + nb;
    unsigned* packed = (unsigned*)(gfill + nb);

    hipMemsetAsync(cnt, 0, (size_t)nb * sizeof(int), stream);
    hipMemsetAsync(gfill, 0, (size_t)nb * sizeof(int), stream);

    int nblk = (E + CHUNK - 1) / CHUNK;  // 196
    size_t lds1 = (size_t)nb * sizeof(int);
    size_t lds2 = (size_t)2 * nb * sizeof(int);
    countA_kernel<<<nblk, BIG, lds1, stream>>>(row, cnt, E, nb);
    scan_kernel<<<1, 1024, 0, stream>>>(cnt, offs, nb);
    binB_kernel<<<nblk, BIG, lds2, stream>>>(row, col, offs, gfill, packed, E, nb);
    phase2_kernel<<<nb, 256, 0, stream>>>(x, packed, offs, cnt, out, N);
}

// Round 9
// 74.308 us; speedup vs baseline: 11.9239x; 1.0518x over previous
//
#include <hip/hip_runtime.h>

#define D_FEAT 32
#define BNODES 32             // nodes per coarse bucket
#define LOG_BN 5
#define NB_CAP 4096           // max buckets the scan supports (1024 thr x 4)
#define CHUNK 8192            // edges per binning block
#define BIG 1024              // threads for binning kernels
#define ECHUNK 1024           // edges per in-block sort chunk (phase 2)
#define CMASK 0x1FFFFu        // low 17 bits = col

// ---- zero cnt+gfill (adjacent) in one tiny dispatch ----
__global__ void zero_kernel(int* __restrict__ p, int n) {
    int i = blockIdx.x * blockDim.x + threadIdx.x;
    if (i < n) p[i] = 0;
}

// ---- pass A: per-block LDS histogram, one global atomic per bucket ----
__global__ void __launch_bounds__(BIG) countA_kernel(const int* __restrict__ row,
                                                     int* __restrict__ cnt,
                                                     int E, int nb) {
    extern __shared__ int hist[];
    int t = threadIdx.x;
    for (int i = t; i < nb; i += BIG) hist[i] = 0;
    __syncthreads();
    int s = blockIdx.x * CHUNK;
    int e_end = min(E, s + CHUNK);
    int e = s + t * 4;
    for (; e + 3 < e_end; e += BIG * 4) {
        int4 r4 = *(const int4*)&row[e];
        atomicAdd(&hist[r4.x >> LOG_BN], 1);
        atomicAdd(&hist[r4.y >> LOG_BN], 1);
        atomicAdd(&hist[r4.z >> LOG_BN], 1);
        atomicAdd(&hist[r4.w >> LOG_BN], 1);
    }
    for (int e2 = e; e2 < e_end; ++e2)
        atomicAdd(&hist[row[e2] >> LOG_BN], 1);
    __syncthreads();
    for (int i = t; i < nb; i += BIG) {
        int h = hist[i];
        if (h) atomicAdd(&cnt[i], h);
    }
}

// ---- exclusive scan of nb (<=4096) counters, single 1024-thread block ----
__global__ void __launch_bounds__(1024) scan_kernel(const int* __restrict__ cnt,
                                                    int* __restrict__ offs, int nb) {
    __shared__ int sh[1024];
    int t = threadIdx.x;
    int base = t * 4;
    int v0 = (base + 0 < nb) ? cnt[base + 0] : 0;
    int v1 = (base + 1 < nb) ? cnt[base + 1] : 0;
    int v2 = (base + 2 < nb) ? cnt[base + 2] : 0;
    int v3 = (base + 3 < nb) ? cnt[base + 3] : 0;
    int s = v0 + v1 + v2 + v3;
    sh[t] = s;
    __syncthreads();
    for (int off = 1; off < 1024; off <<= 1) {
        int v = (t >= off) ? sh[t - off] : 0;
        __syncthreads();
        sh[t] += v;
        __syncthreads();
    }
    int p = sh[t] - s;
    if (base + 0 < nb) offs[base + 0] = p; p += v0;
    if (base + 1 < nb) offs[base + 1] = p; p += v1;
    if (base + 2 < nb) offs[base + 2] = p; p += v2;
    if (base + 3 < nb) offs[base + 3] = p;
}

// ---- pass B: re-histogram chunk, reserve ranges, emit packed ----
__global__ void __launch_bounds__(BIG) binB_kernel(const int* __restrict__ row,
                                                   const int* __restrict__ col,
                                                   const int* __restrict__ offs,
                                                   int* __restrict__ gfill,
                                                   unsigned* __restrict__ packed,
                                                   int E, int nb) {
    extern __shared__ int shmem[];
    int* hist = shmem;
    int* base = shmem + nb;
    int t = threadIdx.x;
    for (int i = t; i < nb; i += BIG) hist[i] = 0;
    __syncthreads();
    int s = blockIdx.x * CHUNK;
    int e_end = min(E, s + CHUNK);

    // histogram (int4)
    int e = s + t * 4;
    for (; e + 3 < e_end; e += BIG * 4) {
        int4 r4 = *(const int4*)&row[e];
        atomicAdd(&hist[r4.x >> LOG_BN], 1);
        atomicAdd(&hist[r4.y >> LOG_BN], 1);
        atomicAdd(&hist[r4.z >> LOG_BN], 1);
        atomicAdd(&hist[r4.w >> LOG_BN], 1);
    }
    for (int e2 = e; e2 < e_end; ++e2)
        atomicAdd(&hist[row[e2] >> LOG_BN], 1);
    __syncthreads();

    // reserve contiguous ranges: one global atomic per (block,bucket)
    for (int i = t; i < nb; i += BIG) {
        int h = hist[i];
        base[i] = h ? (offs[i] + atomicAdd(&gfill[i], h)) : 0;
    }
    __syncthreads();

    // scatter (int4 on row and col)
    e = s + t * 4;
    for (; e + 3 < e_end; e += BIG * 4) {
        int4 r4 = *(const int4*)&row[e];
        int4 c4 = *(const int4*)&col[e];
        int b, slot;
        b = r4.x >> LOG_BN; slot = base[b] + atomicAdd(&hist[b], -1) - 1;
        packed[slot] = ((unsigned)(r4.x & (BNODES - 1)) << 17) | (unsigned)c4.x;
        b = r4.y >> LOG_BN; slot = base[b] + atomicAdd(&hist[b], -1) - 1;
        packed[slot] = ((unsigned)(r4.y & (BNODES - 1)) << 17) | (unsigned)c4.y;
        b = r4.z >> LOG_BN; slot = base[b] + atomicAdd(&hist[b], -1) - 1;
        packed[slot] = ((unsigned)(r4.z & (BNODES - 1)) << 17) | (unsigned)c4.z;
        b = r4.w >> LOG_BN; slot = base[b] + atomicAdd(&hist[b], -1) - 1;
        packed[slot] = ((unsigned)(r4.w & (BNODES - 1)) << 17) | (unsigned)c4.w;
    }
    for (int e2 = e; e2 < e_end; ++e2) {
        int r = row[e2];
        int c = col[e2];
        int b = r >> LOG_BN;
        int slot = base[b] + atomicAdd(&hist[b], -1) - 1;
        packed[slot] = ((unsigned)(r & (BNODES - 1)) << 17) | (unsigned)c;
    }
}

// ---- phase 2: in-block counting sort + register-accumulated reduce ----
__global__ void __launch_bounds__(256) phase2_kernel(const float* __restrict__ x,
                                                     const unsigned* __restrict__ packed,
                                                     const int* __restrict__ offs,
                                                     const int* __restrict__ cnt,
                                                     float* __restrict__ out, int N) {
    __shared__ unsigned scol[ECHUNK];   // 4 KB: row-sorted packed entries
    __shared__ int hist[BNODES];
    __shared__ int hoff[BNODES];
    int t = threadIdx.x;
    int b = blockIdx.x;
    int s = offs[b];
    int n = cnt[b];
    int node = t >> 3;
    int j = t & 7;
    const float4* x4 = (const float4*)x;

    float4 acc = make_float4(0.f, 0.f, 0.f, 0.f);
    int mydeg = 0;

    for (int cs = 0; cs < n; cs += ECHUNK) {
        int m = min(ECHUNK, n - cs);
        if (t < BNODES) hist[t] = 0;
        __syncthreads();
        for (int i = t; i < m; i += 256)
            atomicAdd(&hist[packed[s + cs + i] >> 17], 1);
        __syncthreads();
        if (t < 64) {
            int v = (t < BNODES) ? hist[t] : 0;
            int sum = v;
            #pragma unroll
            for (int off = 1; off < BNODES; off <<= 1) {
                int w = __shfl_up(sum, off);
                if (t >= off) sum += w;
            }
            if (t < BNODES) hoff[t] = sum - v;
        }
        __syncthreads();
        int mcount = hist[node];
        int mbase = hoff[node];
        mydeg += mcount;
        __syncthreads();
        for (int i = t; i < m; i += 256) {
            unsigned p = packed[s + cs + i];
            int r = p >> 17;
            int slot = hoff[r] + atomicAdd(&hist[r], -1) - 1;
            scol[slot] = p;
        }
        __syncthreads();
        int i = 0;
        for (; i + 3 < mcount; i += 4) {
            unsigned c0 = scol[mbase + i + 0] & CMASK;
            unsigned c1 = scol[mbase + i + 1] & CMASK;
            unsigned c2 = scol[mbase + i + 2] & CMASK;
            unsigned c3 = scol[mbase + i + 3] & CMASK;
            float4 v0 = x4[c0 * 8 + j];
            float4 v1 = x4[c1 * 8 + j];
            float4 v2 = x4[c2 * 8 + j];
            float4 v3 = x4[c3 * 8 + j];
            acc.x += v0.x; acc.y += v0.y; acc.z += v0.z; acc.w += v0.w;
            acc.x += v1.x; acc.y += v1.y; acc.z += v1.z; acc.w += v1.w;
            acc.x += v2.x; acc.y += v2.y; acc.z += v2.z; acc.w += v2.w;
            acc.x += v3.x; acc.y += v3.y; acc.z += v3.z; acc.w += v3.w;
        }
        for (; i < mcount; ++i) {
            unsigned c = scol[mbase + i] & CMASK;
            float4 v = x4[c * 8 + j];
            acc.x += v.x; acc.y += v.y; acc.z += v.z; acc.w += v.w;
        }
        __syncthreads();
    }

    int gnode = b * BNODES + node;
    if (gnode < N) {
        float invd = 1.0f / fmaxf((float)mydeg, 1.0f);
        float4 v;
        v.x = acc.x * invd; v.y = acc.y * invd;
        v.z = acc.z * invd; v.w = acc.w * invd;
        ((float4*)out)[(size_t)gnode * 8 + j] = v;
    }
}

// ---------------- launch ----------------

extern "C" void kernel_launch(void* const* d_in, const int* in_sizes, int n_in,
                              void* d_out, int out_size, void* d_ws, size_t ws_size,
                              hipStream_t stream) {
    const float* x = (const float*)d_in[0];
    const int* edge_index = (const int*)d_in[1];

    int E = in_sizes[1] / 2;
    const int* row = edge_index;      // edge_index[0]
    const int* col = edge_index + E;  // edge_index[1]
    int N = in_sizes[0] / D_FEAT;

    float* out = (float*)d_out;

    int nb = (N + BNODES - 1) / BNODES;  // 3125 buckets
    if (nb > NB_CAP) nb = NB_CAP;

    // ws layout (ints): cnt[nb] | gfill[nb] | offs[nb] | packed[E]
    // (cnt and gfill adjacent so one zero kernel covers both)
    int* cnt   = (int*)d_ws;
    int* gfill = cnt + nb;
    int* offs  = gfill + nb;
    unsigned* packed = (unsigned*)(offs + nb);

    int nzero = 2 * nb;
    zero_kernel<<<(nzero + 255) / 256, 256, 0, stream>>>(cnt, nzero);

    int nblk = (E + CHUNK - 1) / CHUNK;  // 196
    size_t lds1 = (size_t)nb * sizeof(int);
    size_t lds2 = (size_t)2 * nb * sizeof(int);
    countA_kernel<<<nblk, BIG, lds1, stream>>>(row, cnt, E, nb);
    scan_kernel<<<1, 1024, 0, stream>>>(cnt, offs, nb);
    binB_kernel<<<nblk, BIG, lds2, stream>>>(row, col, offs, gfill, packed, E, nb);
    phase2_kernel<<<nb, 256, 0, stream>>>(x, packed, offs, cnt, out, N);
}